// Round 1
// baseline (4887.157 us; speedup 1.0000x reference)
//
#include <hip/hip_runtime.h>
#include <hip/hip_bf16.h>
#include <math.h>

#define NTOK 4096
#define DIM 2048
#define NHEAD 1002
#define C0LO 1000
#define C0HI 10000
#define C1HI 50257
#define OSZ0 9000
#define OSZ1 40257
#define H0S 512
#define H1S 128
#define JSPLIT0 2
#define JSPLIT1 4

__device__ __forceinline__ float blockReduceMax(float v, float* red) {
  int tid = threadIdx.x;
  red[tid] = v; __syncthreads();
  for (int off = 128; off > 0; off >>= 1) {
    if (tid < off) red[tid] = fmaxf(red[tid], red[tid + off]);
    __syncthreads();
  }
  float r = red[0]; __syncthreads();
  return r;
}

__device__ __forceinline__ float blockReduceSum(float v, float* red) {
  int tid = threadIdx.x;
  red[tid] = v; __syncthreads();
  for (int off = 128; off > 0; off >>= 1) {
    if (tid < off) red[tid] += red[tid + off];
    __syncthreads();
  }
  float r = red[0]; __syncthreads();
  return r;
}

// C[M,N] = A[M,K] * B[N,K]^T  (row-major), fp32 tiled 64x64x16, 256 threads
__global__ __launch_bounds__(256) void gemm_nt(
    const float* __restrict__ A, const float* __restrict__ B,
    float* __restrict__ C, int M, int N, int K) {
  __shared__ float As[16][64];
  __shared__ float Bs[16][64];
  int tid = threadIdx.x;
  int tx = tid & 15, ty = tid >> 4;
  int row0 = blockIdx.y * 64, col0 = blockIdx.x * 64;
  float acc[4][4] = {};
  for (int k0 = 0; k0 < K; k0 += 16) {
    {
      int linear = tid * 4;
      int r = linear >> 4;
      int c = linear & 15;
      int gr = row0 + r;
      float4 v = {0.f, 0.f, 0.f, 0.f};
      if (gr < M) v = *reinterpret_cast<const float4*>(&A[(size_t)gr * K + k0 + c]);
      As[c + 0][r] = v.x; As[c + 1][r] = v.y; As[c + 2][r] = v.z; As[c + 3][r] = v.w;
      int gn = col0 + r;
      float4 w = {0.f, 0.f, 0.f, 0.f};
      if (gn < N) w = *reinterpret_cast<const float4*>(&B[(size_t)gn * K + k0 + c]);
      Bs[c + 0][r] = w.x; Bs[c + 1][r] = w.y; Bs[c + 2][r] = w.z; Bs[c + 3][r] = w.w;
    }
    __syncthreads();
#pragma unroll
    for (int k = 0; k < 16; ++k) {
      float4 a = *reinterpret_cast<const float4*>(&As[k][ty * 4]);
      float4 b = *reinterpret_cast<const float4*>(&Bs[k][tx * 4]);
      acc[0][0] += a.x * b.x; acc[0][1] += a.x * b.y; acc[0][2] += a.x * b.z; acc[0][3] += a.x * b.w;
      acc[1][0] += a.y * b.x; acc[1][1] += a.y * b.y; acc[1][2] += a.y * b.z; acc[1][3] += a.y * b.w;
      acc[2][0] += a.z * b.x; acc[2][1] += a.z * b.y; acc[2][2] += a.z * b.z; acc[2][3] += a.z * b.w;
      acc[3][0] += a.w * b.x; acc[3][1] += a.w * b.y; acc[3][2] += a.w * b.z; acc[3][3] += a.w * b.w;
    }
    __syncthreads();
  }
#pragma unroll
  for (int i = 0; i < 4; ++i) {
    int gr = row0 + ty * 4 + i;
    if (gr >= M) continue;
#pragma unroll
    for (int j = 0; j < 4; ++j) {
      int gc = col0 + tx * 4 + j;
      if (gc < N) C[(size_t)gr * N + gc] = acc[i][j];
    }
  }
}

__global__ __launch_bounds__(256) void head_finish(
    const float* __restrict__ head, const int* __restrict__ target,
    float* __restrict__ lse_head, float* __restrict__ head_tgt,
    float* __restrict__ cl0, float* __restrict__ cl1) {
  __shared__ float red[256];
  int i = blockIdx.x, tid = threadIdx.x;
  const float* row = head + (size_t)i * NHEAD;
  float m = -INFINITY;
  for (int j = tid; j < NHEAD; j += 256) m = fmaxf(m, row[j]);
  m = blockReduceMax(m, red);
  float s = 0.f;
  for (int j = tid; j < NHEAD; j += 256) s += expf(row[j] - m);
  s = blockReduceSum(s, red);
  if (tid == 0) {
    int t = target[i];
    lse_head[i] = m + logf(s);
    head_tgt[i] = row[t < C0LO ? t : 0];
    cl0[i] = row[C0LO];
    cl1[i] = row[C0LO + 1];
  }
}

// Online logsumexp over tail logits = h[NTOK,H] @ W2[osz,H]^T, never materialized.
// Block: TT tokens x (j-range slice). 256 threads = 4 warps; warp owns 8 token rows.
template <int H, int TT, int JSPLIT>
__global__ __launch_bounds__(256) void tail_lse(
    const float* __restrict__ h, const float* __restrict__ W2,
    int osz, float* __restrict__ pm, float* __restrict__ ps) {
  const int BN = 64, BKC = 64;
  const int R = TT / 4;  // rows per warp
  __shared__ float Hs[H][TT];
  __shared__ float Bs[BKC][BN];
  __shared__ float rm[TT], rs[TT];
  int tid = threadIdx.x;
  int lane = tid & 63, warp = tid >> 6;
  int tok0 = blockIdx.x * TT;
  int len = (osz + JSPLIT - 1) / JSPLIT;
  int jlo = blockIdx.y * len;
  int jhi = min(osz, jlo + len);

  for (int e = tid * 4; e < TT * H; e += 256 * 4) {
    int tok = e / H, k = e % H;
    float4 v = *reinterpret_cast<const float4*>(&h[(size_t)(tok0 + tok) * H + k]);
    Hs[k + 0][tok] = v.x; Hs[k + 1][tok] = v.y; Hs[k + 2][tok] = v.z; Hs[k + 3][tok] = v.w;
  }
  if (tid < TT) { rm[tid] = -INFINITY; rs[tid] = 0.f; }
  __syncthreads();

  for (int j0 = jlo; j0 < jhi; j0 += BN) {
    float acc[R];
#pragma unroll
    for (int q = 0; q < R; ++q) acc[q] = 0.f;
    for (int k0 = 0; k0 < H; k0 += BKC) {
      __syncthreads();
      for (int e = tid * 4; e < BN * BKC; e += 1024) {
        int jj = e >> 6, k = e & 63;
        float4 v = {0.f, 0.f, 0.f, 0.f};
        if (j0 + jj < jhi) v = *reinterpret_cast<const float4*>(&W2[(size_t)(j0 + jj) * H + k0 + k]);
        Bs[k + 0][jj] = v.x; Bs[k + 1][jj] = v.y; Bs[k + 2][jj] = v.z; Bs[k + 3][jj] = v.w;
      }
      __syncthreads();
#pragma unroll 8
      for (int k = 0; k < BKC; ++k) {
        float b = Bs[k][lane];
#pragma unroll
        for (int q4 = 0; q4 < R; q4 += 4) {
          float4 a = *reinterpret_cast<const float4*>(&Hs[k0 + k][warp * R + q4]);
          acc[q4 + 0] += a.x * b;
          acc[q4 + 1] += a.y * b;
          acc[q4 + 2] += a.z * b;
          acc[q4 + 3] += a.w * b;
        }
      }
    }
    bool valid = (j0 + lane < jhi);
#pragma unroll
    for (int q = 0; q < R; ++q) {
      float v = valid ? acc[q] : -INFINITY;
      float m = v;
      for (int off = 32; off > 0; off >>= 1) m = fmaxf(m, __shfl_xor(m, off));
      float e = valid ? expf(v - m) : 0.f;
      for (int off = 32; off > 0; off >>= 1) e += __shfl_xor(e, off);
      if (lane == 0) {
        int r = warp * R + q;
        float om = rm[r];
        float nm = fmaxf(om, m);
        rs[r] = rs[r] * expf(om - nm) + e * expf(m - nm);
        rm[r] = nm;
      }
    }
  }
  __syncthreads();
  if (tid < TT) {
    pm[(size_t)blockIdx.y * NTOK + tok0 + tid] = rm[tid];
    ps[(size_t)blockIdx.y * NTOK + tok0 + tid] = rs[tid];
  }
}

__global__ __launch_bounds__(256) void finalize(
    const int* __restrict__ target,
    const float* __restrict__ lse_head, const float* __restrict__ head_tgt,
    const float* __restrict__ cl0, const float* __restrict__ cl1,
    const float* __restrict__ h0, const float* __restrict__ h1,
    const float* __restrict__ W2_0, const float* __restrict__ W2_1,
    const float* __restrict__ pm0, const float* __restrict__ ps0,
    const float* __restrict__ pm1, const float* __restrict__ ps1,
    float* __restrict__ outv, float* __restrict__ d_out) {
  __shared__ float red[256];
  int i = blockIdx.x;
  int tid = threadIdx.x;
  int t = target[i];
  float res = 0.f;
  if (t < C0LO) {
    res = head_tgt[i] - lse_head[i];
  } else {
    int c = (t < C0HI) ? 0 : 1;
    int H = c ? H1S : H0S;
    int low = c ? C0HI : C0LO;
    const float* hv = (c ? h1 : h0) + (size_t)i * H;
    const float* wv = (c ? W2_1 : W2_0) + (size_t)(t - low) * H;
    float p = 0.f;
    for (int k = tid; k < H; k += 256) p += hv[k] * wv[k];
    float dot = blockReduceSum(p, red);
    const float* pm = c ? pm1 : pm0;
    const float* ps = c ? ps1 : ps0;
    int js = c ? JSPLIT1 : JSPLIT0;
    float m = -INFINITY;
    for (int s = 0; s < js; ++s) m = fmaxf(m, pm[(size_t)s * NTOK + i]);
    float S = 0.f;
    for (int s = 0; s < js; ++s) S += ps[(size_t)s * NTOK + i] * expf(pm[(size_t)s * NTOK + i] - m);
    float lse = m + logf(S);
    float clv = c ? cl1[i] : cl0[i];
    res = (clv - lse_head[i]) + (dot - lse);
  }
  if (tid == 0) { outv[i] = res; d_out[i] = res; }
}

__global__ __launch_bounds__(256) void loss_kernel(
    const float* __restrict__ outv, float* __restrict__ d_out) {
  __shared__ float red[256];
  int tid = threadIdx.x;
  float s = 0.f;
  for (int j = tid; j < NTOK; j += 256) s += outv[j];
  s = blockReduceSum(s, red);
  if (tid == 0) d_out[NTOK] = -s / (float)NTOK;
}

extern "C" void kernel_launch(void* const* d_in, const int* in_sizes, int n_in,
                              void* d_out, int out_size, void* d_ws, size_t ws_size,
                              hipStream_t stream) {
  (void)in_sizes; (void)n_in; (void)out_size; (void)ws_size;
  const float* x = (const float*)d_in[0];
  const int* target = (const int*)d_in[1];
  const float* W_head = (const float*)d_in[2];
  const float* W1_0 = (const float*)d_in[3];
  const float* W2_0 = (const float*)d_in[4];
  const float* W1_1 = (const float*)d_in[5];
  const float* W2_1 = (const float*)d_in[6];
  float* out = (float*)d_out;
  float* ws = (float*)d_ws;

  size_t off = 0;
  float* head = ws + off;     off += (size_t)NTOK * NHEAD;
  float* h0 = ws + off;       off += (size_t)NTOK * H0S;
  float* h1 = ws + off;       off += (size_t)NTOK * H1S;
  float* lse_head = ws + off; off += NTOK;
  float* head_tgt = ws + off; off += NTOK;
  float* cl0 = ws + off;      off += NTOK;
  float* cl1 = ws + off;      off += NTOK;
  float* pm0 = ws + off;      off += (size_t)JSPLIT0 * NTOK;
  float* ps0 = ws + off;      off += (size_t)JSPLIT0 * NTOK;
  float* pm1 = ws + off;      off += (size_t)JSPLIT1 * NTOK;
  float* ps1 = ws + off;      off += (size_t)JSPLIT1 * NTOK;
  float* outv = ws + off;     off += NTOK;

  dim3 blk(256);
  gemm_nt<<<dim3((NHEAD + 63) / 64, NTOK / 64), blk, 0, stream>>>(x, W_head, head, NTOK, NHEAD, DIM);
  gemm_nt<<<dim3(H0S / 64, NTOK / 64), blk, 0, stream>>>(x, W1_0, h0, NTOK, H0S, DIM);
  gemm_nt<<<dim3(H1S / 64, NTOK / 64), blk, 0, stream>>>(x, W1_1, h1, NTOK, H1S, DIM);
  head_finish<<<NTOK, blk, 0, stream>>>(head, target, lse_head, head_tgt, cl0, cl1);
  tail_lse<H0S, 32, JSPLIT0><<<dim3(NTOK / 32, JSPLIT0), blk, 0, stream>>>(h0, W2_0, OSZ0, pm0, ps0);
  tail_lse<H1S, 32, JSPLIT1><<<dim3(NTOK / 32, JSPLIT1), blk, 0, stream>>>(h1, W2_1, OSZ1, pm1, ps1);
  finalize<<<NTOK, blk, 0, stream>>>(target, lse_head, head_tgt, cl0, cl1, h0, h1, W2_0, W2_1,
                                     pm0, ps0, pm1, ps1, outv, out);
  loss_kernel<<<1, blk, 0, stream>>>(outv, out);
}

// Round 2
// 319.686 us; speedup vs baseline: 15.2873x; 15.2873x over previous
//
#include <hip/hip_runtime.h>
#include <hip/hip_bf16.h>
#include <math.h>

#define NTOK 4096
#define DIM 2048
#define NHEAD 1002
#define C0LO 1000
#define C0HI 10000
#define OSZ0 9000
#define OSZ1 40257
#define H0S 512
#define H1S 128
#define JS0 16
#define JS1 16

typedef __attribute__((ext_vector_type(4))) short short4v;
typedef __attribute__((ext_vector_type(8))) short short8v;
typedef __attribute__((ext_vector_type(4))) float f32x4;
typedef __hip_bfloat16 bf16;

#define GLOBAL_AS __attribute__((address_space(1)))
#define LDS_AS __attribute__((address_space(3)))

__device__ __forceinline__ float blockReduceMax(float v, float* red) {
  int tid = threadIdx.x;
  red[tid] = v; __syncthreads();
  for (int off = 128; off > 0; off >>= 1) {
    if (tid < off) red[tid] = fmaxf(red[tid], red[tid + off]);
    __syncthreads();
  }
  float r = red[0]; __syncthreads();
  return r;
}

__device__ __forceinline__ float blockReduceSum(float v, float* red) {
  int tid = threadIdx.x;
  red[tid] = v; __syncthreads();
  for (int off = 128; off > 0; off >>= 1) {
    if (tid < off) red[tid] += red[tid + off];
    __syncthreads();
  }
  float r = red[0]; __syncthreads();
  return r;
}

// fp32 -> bf16 convert, 4 elems/thread
__global__ __launch_bounds__(256) void f2b(const float* __restrict__ in,
                                           bf16* __restrict__ out, int n) {
  int i = (blockIdx.x * 256 + threadIdx.x) * 4;
  if (i >= n) return;
  float4 v = *reinterpret_cast<const float4*>(in + i);
  out[i + 0] = __float2bfloat16(v.x);
  out[i + 1] = __float2bfloat16(v.y);
  out[i + 2] = __float2bfloat16(v.z);
  out[i + 3] = __float2bfloat16(v.w);
}

// Stage a [128 rows][64 bf16] tile into LDS (row-major, 128B/row) via
// global_load_lds width=16, with 16B-slot XOR swizzle applied on the
// GLOBAL source side (LDS dest stays linear): LDS[row][s] = g[row][s^(row&7)].
__device__ __forceinline__ void stage_tile(const bf16* __restrict__ g, int row0,
                                           int maxrow, int ld, int k0,
                                           char* lds, int wave, int lane) {
#pragma unroll
  for (int c = 0; c < 4; ++c) {
    int rbase = wave * 32 + c * 8;
    int row = rbase + (lane >> 3);
    int grow = row0 + row;
    grow = grow < maxrow ? grow : maxrow;
    int slot = (lane & 7) ^ (row & 7);
    const bf16* src = g + (size_t)grow * ld + k0 + slot * 8;
    __builtin_amdgcn_global_load_lds((const GLOBAL_AS unsigned int*)src,
                                     (LDS_AS unsigned int*)(lds + rbase * 128),
                                     16, 0, 0);
  }
}

// Read one A/B fragment for mfma_f32_16x16x32_bf16.
// k-halves: elems 0-3 -> k = kk*32 + (lane>>4)*4 + e ; elems 4-7 -> +16.
// Applies the matching 16B-slot XOR swizzle on the read.
__device__ __forceinline__ short8v read_frag(const char* lds, int row, int kk, int lane) {
  int g = lane >> 4;
  int r7 = row & 7;
  int b1 = kk * 64 + g * 8;
  int b2 = b1 + 32;
  b1 = ((b1 >> 4) ^ r7) * 16 + (b1 & 15);
  b2 = ((b2 >> 4) ^ r7) * 16 + (b2 & 15);
  const char* p = lds + row * 128;
  short4v lo = *reinterpret_cast<const short4v*>(p + b1);
  short4v hi = *reinterpret_cast<const short4v*>(p + b2);
  return __builtin_shufflevector(lo, hi, 0, 1, 2, 3, 4, 5, 6, 7);
}

// C[M,N] = A[M,K] * B[N,K]^T, bf16 in / fp32 out (+optional bf16 copy).
// 128x128 tile, BK=64, 4 waves, each wave a 64x64 quadrant (4x4 16x16 frags).
__global__ __launch_bounds__(256, 2) void gemm_mfma(
    const bf16* __restrict__ A, const bf16* __restrict__ B,
    float* __restrict__ C, bf16* __restrict__ C2, int M, int N, int K) {
  __shared__ __align__(16) char As[128 * 128];
  __shared__ __align__(16) char Bs[128 * 128];
  int tid = threadIdx.x;
  int lane = tid & 63, wave = tid >> 6;
  int wr = wave >> 1, wc = wave & 1;
  int row0 = blockIdx.y * 128, col0 = blockIdx.x * 128;
  f32x4 acc[4][4] = {};
  for (int k0 = 0; k0 < K; k0 += 64) {
    __syncthreads();
    stage_tile(A, row0, M - 1, K, k0, As, wave, lane);
    stage_tile(B, col0, N - 1, K, k0, Bs, wave, lane);
    __syncthreads();
#pragma unroll
    for (int kk = 0; kk < 2; ++kk) {
      short8v af[4], bfr[4];
#pragma unroll
      for (int m = 0; m < 4; ++m)
        af[m] = read_frag(As, wr * 64 + m * 16 + (lane & 15), kk, lane);
#pragma unroll
      for (int n = 0; n < 4; ++n)
        bfr[n] = read_frag(Bs, wc * 64 + n * 16 + (lane & 15), kk, lane);
#pragma unroll
      for (int m = 0; m < 4; ++m)
#pragma unroll
        for (int n = 0; n < 4; ++n)
          acc[m][n] = __builtin_amdgcn_mfma_f32_16x16x32_bf16(af[m], bfr[n], acc[m][n], 0, 0, 0);
    }
  }
#pragma unroll
  for (int m = 0; m < 4; ++m) {
    int row = row0 + wr * 64 + m * 16 + (lane >> 4) * 4;
#pragma unroll
    for (int n = 0; n < 4; ++n) {
      int col = col0 + wc * 64 + n * 16 + (lane & 15);
      if (col < N) {
#pragma unroll
        for (int r = 0; r < 4; ++r) {
          C[(size_t)(row + r) * N + col] = acc[m][n][r];
          if (C2) C2[(size_t)(row + r) * N + col] = __float2bfloat16(acc[m][n][r]);
        }
      }
    }
  }
}

// Tail online sum-exp: never materializes logits = h @ W2^T.
// Same GEMM skeleton; per j-tile epilogue accumulates exp(logit) into
// per-lane row partials. No max subtraction (logits are O(1)).
template <int H, int OSZ, int JSPLIT>
__global__ __launch_bounds__(256, 2) void tail_lse_mfma(
    const bf16* __restrict__ Ab, const bf16* __restrict__ W2b,
    float* __restrict__ ps) {
  __shared__ __align__(16) char As[128 * 128];
  __shared__ __align__(16) char Bs[128 * 128];
  __shared__ float reds[128];
  int tid = threadIdx.x;
  int lane = tid & 63, wave = tid >> 6;
  int wr = wave >> 1, wc = wave & 1;
  int tok0 = blockIdx.x * 128;
  const int NT = (OSZ + 127) / 128;
  const int TPS = (NT + JSPLIT - 1) / JSPLIT;
  int t_lo = blockIdx.y * TPS;
  int t_hi = min(NT, t_lo + TPS);
  float srun[4][4] = {};  // [m-frag][reg] per-lane partial sums
  for (int jt = t_lo; jt < t_hi; ++jt) {
    int j0 = jt * 128;
    f32x4 acc[4][4] = {};
    for (int k0 = 0; k0 < H; k0 += 64) {
      __syncthreads();
      stage_tile(Ab, tok0, NTOK - 1, H, k0, As, wave, lane);
      stage_tile(W2b, j0, OSZ - 1, H, k0, Bs, wave, lane);
      __syncthreads();
#pragma unroll
      for (int kk = 0; kk < 2; ++kk) {
        short8v af[4], bfr[4];
#pragma unroll
        for (int m = 0; m < 4; ++m)
          af[m] = read_frag(As, wr * 64 + m * 16 + (lane & 15), kk, lane);
#pragma unroll
        for (int n = 0; n < 4; ++n)
          bfr[n] = read_frag(Bs, wc * 64 + n * 16 + (lane & 15), kk, lane);
#pragma unroll
        for (int m = 0; m < 4; ++m)
#pragma unroll
          for (int n = 0; n < 4; ++n)
            acc[m][n] = __builtin_amdgcn_mfma_f32_16x16x32_bf16(af[m], bfr[n], acc[m][n], 0, 0, 0);
      }
    }
#pragma unroll
    for (int m = 0; m < 4; ++m)
#pragma unroll
      for (int n = 0; n < 4; ++n) {
        int col = j0 + wc * 64 + n * 16 + (lane & 15);
        if (col < OSZ) {
#pragma unroll
          for (int r = 0; r < 4; ++r) srun[m][r] += __expf(acc[m][n][r]);
        }
      }
  }
  // reduce across the 16 lanes of each row-group
#pragma unroll
  for (int off = 1; off < 16; off <<= 1)
#pragma unroll
    for (int m = 0; m < 4; ++m)
#pragma unroll
      for (int r = 0; r < 4; ++r) srun[m][r] += __shfl_xor(srun[m][r], off);
  __syncthreads();
  if (wc == 0 && (lane & 15) == 0) {
#pragma unroll
    for (int m = 0; m < 4; ++m)
#pragma unroll
      for (int r = 0; r < 4; ++r)
        reds[wr * 64 + m * 16 + (lane >> 4) * 4 + r] = srun[m][r];
  }
  __syncthreads();
  if (wc == 1 && (lane & 15) == 0) {
#pragma unroll
    for (int m = 0; m < 4; ++m)
#pragma unroll
      for (int r = 0; r < 4; ++r) {
        int row = wr * 64 + m * 16 + (lane >> 4) * 4 + r;
        ps[(size_t)blockIdx.y * NTOK + tok0 + row] = reds[row] + srun[m][r];
      }
  }
}

__global__ __launch_bounds__(256) void head_finish(
    const float* __restrict__ head, const int* __restrict__ target,
    float* __restrict__ lse_head, float* __restrict__ head_tgt,
    float* __restrict__ cl0, float* __restrict__ cl1) {
  __shared__ float red[256];
  int i = blockIdx.x, tid = threadIdx.x;
  const float* row = head + (size_t)i * NHEAD;
  float m = -INFINITY;
  for (int j = tid; j < NHEAD; j += 256) m = fmaxf(m, row[j]);
  m = blockReduceMax(m, red);
  float s = 0.f;
  for (int j = tid; j < NHEAD; j += 256) s += expf(row[j] - m);
  s = blockReduceSum(s, red);
  if (tid == 0) {
    int t = target[i];
    lse_head[i] = m + logf(s);
    head_tgt[i] = row[t < C0LO ? t : 0];
    cl0[i] = row[C0LO];
    cl1[i] = row[C0LO + 1];
  }
}

__global__ __launch_bounds__(256) void finalize(
    const int* __restrict__ target,
    const float* __restrict__ lse_head, const float* __restrict__ head_tgt,
    const float* __restrict__ cl0, const float* __restrict__ cl1,
    const float* __restrict__ h0, const float* __restrict__ h1,
    const float* __restrict__ W2_0, const float* __restrict__ W2_1,
    const float* __restrict__ ps0, const float* __restrict__ ps1,
    float* __restrict__ outv, float* __restrict__ d_out) {
  __shared__ float red[256];
  int i = blockIdx.x;
  int tid = threadIdx.x;
  int t = target[i];
  float res = 0.f;
  if (t < C0LO) {
    res = head_tgt[i] - lse_head[i];
  } else {
    int c = (t < C0HI) ? 0 : 1;
    int H = c ? H1S : H0S;
    int low = c ? C0HI : C0LO;
    const float* hv = (c ? h1 : h0) + (size_t)i * H;
    const float* wv = (c ? W2_1 : W2_0) + (size_t)(t - low) * H;
    float p = 0.f;
    for (int k = tid; k < H; k += 256) p += hv[k] * wv[k];
    float dot = blockReduceSum(p, red);
    const float* ps = c ? ps1 : ps0;
    int js = c ? JS1 : JS0;
    float S = 0.f;
    for (int s = 0; s < js; ++s) S += ps[(size_t)s * NTOK + i];
    float lse = logf(S);
    float clv = c ? cl1[i] : cl0[i];
    res = (clv - lse_head[i]) + (dot - lse);
  }
  if (tid == 0) { outv[i] = res; d_out[i] = res; }
}

__global__ __launch_bounds__(256) void loss_kernel(
    const float* __restrict__ outv, float* __restrict__ d_out) {
  __shared__ float red[256];
  int tid = threadIdx.x;
  float s = 0.f;
  for (int j = tid; j < NTOK; j += 256) s += outv[j];
  s = blockReduceSum(s, red);
  if (tid == 0) d_out[NTOK] = -s / (float)NTOK;
}

extern "C" void kernel_launch(void* const* d_in, const int* in_sizes, int n_in,
                              void* d_out, int out_size, void* d_ws, size_t ws_size,
                              hipStream_t stream) {
  (void)in_sizes; (void)n_in; (void)out_size; (void)ws_size;
  const float* x = (const float*)d_in[0];
  const int* target = (const int*)d_in[1];
  const float* W_head = (const float*)d_in[2];
  const float* W1_0 = (const float*)d_in[3];
  const float* W2_0 = (const float*)d_in[4];
  const float* W1_1 = (const float*)d_in[5];
  const float* W2_1 = (const float*)d_in[6];
  float* out = (float*)d_out;

  char* w = (char*)d_ws;
  size_t off = 0;
  auto alloc = [&](size_t bytes) -> void* {
    void* p = w + off;
    off = (off + bytes + 255) & ~(size_t)255;
    return p;
  };
  bf16* xb   = (bf16*)alloc((size_t)NTOK * DIM * 2);
  bf16* Whb  = (bf16*)alloc((size_t)NHEAD * DIM * 2);
  bf16* W10b = (bf16*)alloc((size_t)H0S * DIM * 2);
  bf16* W20b = (bf16*)alloc((size_t)OSZ0 * H0S * 2);
  bf16* W11b = (bf16*)alloc((size_t)H1S * DIM * 2);
  bf16* W21b = (bf16*)alloc((size_t)OSZ1 * H1S * 2);
  float* head = (float*)alloc((size_t)NTOK * NHEAD * 4);
  float* h0   = (float*)alloc((size_t)NTOK * H0S * 4);
  bf16*  h0b  = (bf16*)alloc((size_t)NTOK * H0S * 2);
  float* h1   = (float*)alloc((size_t)NTOK * H1S * 4);
  bf16*  h1b  = (bf16*)alloc((size_t)NTOK * H1S * 2);
  float* lse_head = (float*)alloc(NTOK * 4);
  float* head_tgt = (float*)alloc(NTOK * 4);
  float* cl0 = (float*)alloc(NTOK * 4);
  float* cl1 = (float*)alloc(NTOK * 4);
  float* ps0 = (float*)alloc((size_t)JS0 * NTOK * 4);
  float* ps1 = (float*)alloc((size_t)JS1 * NTOK * 4);
  float* outv = (float*)alloc(NTOK * 4);

  dim3 blk(256);
  auto cvt = [&](const float* src, bf16* dst, int n) {
    f2b<<<dim3((n / 4 + 255) / 256), blk, 0, stream>>>(src, dst, n);
  };
  cvt(x, xb, NTOK * DIM);
  cvt(W_head, Whb, NHEAD * DIM);
  cvt(W1_0, W10b, H0S * DIM);
  cvt(W2_0, W20b, OSZ0 * H0S);
  cvt(W1_1, W11b, H1S * DIM);
  cvt(W2_1, W21b, OSZ1 * H1S);

  gemm_mfma<<<dim3((NHEAD + 127) / 128, NTOK / 128), blk, 0, stream>>>(
      xb, Whb, head, (bf16*)nullptr, NTOK, NHEAD, DIM);
  gemm_mfma<<<dim3(H0S / 128, NTOK / 128), blk, 0, stream>>>(
      xb, W10b, h0, h0b, NTOK, H0S, DIM);
  gemm_mfma<<<dim3(1, NTOK / 128), blk, 0, stream>>>(
      xb, W11b, h1, h1b, NTOK, H1S, DIM);

  head_finish<<<NTOK, blk, 0, stream>>>(head, target, lse_head, head_tgt, cl0, cl1);

  tail_lse_mfma<H0S, OSZ0, JS0><<<dim3(NTOK / 128, JS0), blk, 0, stream>>>(h0b, W20b, ps0);
  tail_lse_mfma<H1S, OSZ1, JS1><<<dim3(NTOK / 128, JS1), blk, 0, stream>>>(h1b, W21b, ps1);

  finalize<<<NTOK, blk, 0, stream>>>(target, lse_head, head_tgt, cl0, cl1,
                                     h0, h1, W2_0, W2_1, ps0, ps1, outv, out);
  loss_kernel<<<1, blk, 0, stream>>>(outv, out);
}

// Round 3
// 195.086 us; speedup vs baseline: 25.0514x; 1.6387x over previous
//
#include <hip/hip_runtime.h>
#include <hip/hip_bf16.h>
#include <math.h>

#define NTOK 4096
#define DIM 2048
#define NHEAD 1002
#define NCAT 1664
#define C0LO 1000
#define C0HI 10000
#define OSZ0 9000
#define OSZ1 40257
#define H0S 512
#define H1S 128
#define JS0 16
#define JS1 16
#define HEADBLKS 8

typedef __attribute__((ext_vector_type(4))) short short4v;
typedef __attribute__((ext_vector_type(8))) short short8v;
typedef __attribute__((ext_vector_type(4))) float f32x4;
typedef __hip_bfloat16 bf16;

#define GLOBAL_AS __attribute__((address_space(1)))
#define LDS_AS __attribute__((address_space(3)))

#define RAW_BAR() __builtin_amdgcn_s_barrier()
#define SCHED_FENCE() __builtin_amdgcn_sched_barrier(0)
#define WAIT_VM(N) asm volatile("s_waitcnt vmcnt(" #N ")" ::: "memory")
#define WAIT_LGKM0() asm volatile("s_waitcnt lgkmcnt(0)" ::: "memory")

// ---------- fused fp32->bf16 convert + Wcat concat ----------
__global__ __launch_bounds__(256) void cvt_all(
    const float* __restrict__ x, const float* __restrict__ W_head,
    const float* __restrict__ W1_0, const float* __restrict__ W1_1,
    const float* __restrict__ W2_0, const float* __restrict__ W2_1,
    bf16* __restrict__ xb, bf16* __restrict__ Wcat,
    bf16* __restrict__ W20b, bf16* __restrict__ W21b) {
  const long NX = (long)NTOK * DIM / 8;
  const long NC = (long)NCAT * DIM / 8;
  const long N20 = (long)OSZ0 * H0S / 8;
  const long N21 = (long)OSZ1 * H1S / 8;
  long gid = (long)blockIdx.x * 256 + threadIdx.x;
  const float* src = nullptr;
  bf16* dst;
  if (gid < NX) {
    src = x + gid * 8; dst = xb + gid * 8;
  } else if (gid < NX + NC) {
    long o = (gid - NX) * 8;
    int row = (int)(o >> 11), k = (int)(o & 2047);
    dst = Wcat + o;
    if (row < NHEAD) src = W_head + (long)row * DIM + k;
    else if (row < 1024) src = nullptr;              // zero padding rows
    else if (row < 1536) src = W1_0 + (long)(row - 1024) * DIM + k;
    else src = W1_1 + (long)(row - 1536) * DIM + k;
  } else if (gid < NX + NC + N20) {
    long o = (gid - NX - NC) * 8; src = W2_0 + o; dst = W20b + o;
  } else if (gid < NX + NC + N20 + N21) {
    long o = (gid - NX - NC - N20) * 8; src = W2_1 + o; dst = W21b + o;
  } else {
    return;
  }
  union { short8v v; bf16 h[8]; } u;
  if (src) {
    float4 a = *reinterpret_cast<const float4*>(src);
    float4 b = *reinterpret_cast<const float4*>(src + 4);
    u.h[0] = __float2bfloat16(a.x); u.h[1] = __float2bfloat16(a.y);
    u.h[2] = __float2bfloat16(a.z); u.h[3] = __float2bfloat16(a.w);
    u.h[4] = __float2bfloat16(b.x); u.h[5] = __float2bfloat16(b.y);
    u.h[6] = __float2bfloat16(b.z); u.h[7] = __float2bfloat16(b.w);
  } else {
#pragma unroll
    for (int e = 0; e < 8; ++e) u.h[e] = __float2bfloat16(0.f);
  }
  *reinterpret_cast<short8v*>(dst) = u.v;
}

// ---------- 128B-row staging (BK=64), as verified in R2 ----------
__device__ __forceinline__ void stage_tile(const bf16* __restrict__ g, int row0,
                                           int maxrow, int ld, int k0,
                                           char* lds, int wave, int lane) {
#pragma unroll
  for (int c = 0; c < 4; ++c) {
    int rbase = wave * 32 + c * 8;
    int row = rbase + (lane >> 3);
    int grow = row0 + row;
    grow = grow < maxrow ? grow : maxrow;
    int slot = (lane & 7) ^ (row & 7);
    const bf16* src = g + (size_t)grow * ld + k0 + slot * 8;
    __builtin_amdgcn_global_load_lds((const GLOBAL_AS unsigned int*)src,
                                     (LDS_AS unsigned int*)(lds + rbase * 128),
                                     16, 0, 0);
  }
}

__device__ __forceinline__ short8v read_frag(const char* lds, int row, int kk, int lane) {
  int g = lane >> 4;
  int r7 = row & 7;
  int b1 = kk * 64 + g * 8;
  int b2 = b1 + 32;
  b1 = ((b1 >> 4) ^ r7) * 16 + (b1 & 15);
  b2 = ((b2 >> 4) ^ r7) * 16 + (b2 & 15);
  const char* p = lds + row * 128;
  short4v lo = *reinterpret_cast<const short4v*>(p + b1);
  short4v hi = *reinterpret_cast<const short4v*>(p + b2);
  return __builtin_shufflevector(lo, hi, 0, 1, 2, 3, 4, 5, 6, 7);
}

// ---------- 256B-row staging (whole K=128 tile) ----------
__device__ __forceinline__ void stage_tile256(const bf16* __restrict__ g, int row0,
                                              int maxrow, int ld,
                                              char* lds, int wave, int lane) {
#pragma unroll
  for (int c = 0; c < 8; ++c) {
    int rbase = wave * 32 + c * 4;
    int row = rbase + (lane >> 4);
    int grow = row0 + row;
    grow = grow < maxrow ? grow : maxrow;
    int slot = (lane & 15) ^ (row & 7);
    const bf16* src = g + (size_t)grow * ld + slot * 8;
    __builtin_amdgcn_global_load_lds((const GLOBAL_AS unsigned int*)src,
                                     (LDS_AS unsigned int*)(lds + rbase * 256),
                                     16, 0, 0);
  }
}

__device__ __forceinline__ short8v read_frag256(const char* lds, int row, int kk, int lane) {
  int g = lane >> 4;
  int r7 = row & 7;
  int b1 = kk * 64 + g * 8;
  int b2 = b1 + 32;
  b1 = (((b1 >> 4) ^ r7) << 4) | (b1 & 15);
  b2 = (((b2 >> 4) ^ r7) << 4) | (b2 & 15);
  const char* p = lds + row * 256;
  short4v lo = *reinterpret_cast<const short4v*>(p + b1);
  short4v hi = *reinterpret_cast<const short4v*>(p + b2);
  return __builtin_shufflevector(lo, hi, 0, 1, 2, 3, 4, 5, 6, 7);
}

// ---------- fused projection GEMM: C[4096,1664] = xb @ Wcat^T ----------
// cols [0,1002): head logits (fp32) + per-block sum-exp partials
// cols [1024,1536): h0 (fp32 + bf16) ; cols [1536,1664): h1 (fp32 + bf16)
__global__ __launch_bounds__(256, 2) void proj_gemm(
    const bf16* __restrict__ A, const bf16* __restrict__ B,
    float* __restrict__ head, float* __restrict__ h0, bf16* __restrict__ h0b,
    float* __restrict__ h1, bf16* __restrict__ h1b, float* __restrict__ ps_head) {
  __shared__ __align__(16) char As[128 * 128];
  __shared__ __align__(16) char Bs[128 * 128];
  __shared__ float reds[128];
  int tid = threadIdx.x;
  int lane = tid & 63, wave = tid >> 6;
  int wr = wave >> 1, wc = wave & 1;
  int row0 = blockIdx.y * 128, col0 = blockIdx.x * 128;
  f32x4 acc[4][4] = {};
  for (int k0 = 0; k0 < DIM; k0 += 64) {
    __syncthreads();
    stage_tile(A, row0, NTOK - 1, DIM, k0, As, wave, lane);
    stage_tile(B, col0, NCAT - 1, DIM, k0, Bs, wave, lane);
    __syncthreads();
#pragma unroll
    for (int kk = 0; kk < 2; ++kk) {
      short8v af[4], bfr[4];
#pragma unroll
      for (int m = 0; m < 4; ++m)
        af[m] = read_frag(As, wr * 64 + m * 16 + (lane & 15), kk, lane);
#pragma unroll
      for (int n = 0; n < 4; ++n)
        bfr[n] = read_frag(Bs, wc * 64 + n * 16 + (lane & 15), kk, lane);
#pragma unroll
      for (int m = 0; m < 4; ++m)
#pragma unroll
        for (int n = 0; n < 4; ++n)
          acc[m][n] = __builtin_amdgcn_mfma_f32_16x16x32_bf16(af[m], bfr[n], acc[m][n], 0, 0, 0);
    }
  }
  float srun[4][4] = {};
#pragma unroll
  for (int m = 0; m < 4; ++m) {
    int row = row0 + wr * 64 + m * 16 + (lane >> 4) * 4;
#pragma unroll
    for (int n = 0; n < 4; ++n) {
      int col = col0 + wc * 64 + n * 16 + (lane & 15);
#pragma unroll
      for (int r = 0; r < 4; ++r) {
        float v = acc[m][n][r];
        if (col < NHEAD) {
          head[(size_t)(row + r) * NHEAD + col] = v;
          srun[m][r] += __expf(v);
        } else if (col >= 1024 && col < 1536) {
          h0[(size_t)(row + r) * H0S + (col - 1024)] = v;
          h0b[(size_t)(row + r) * H0S + (col - 1024)] = __float2bfloat16(v);
        } else if (col >= 1536) {
          h1[(size_t)(row + r) * H1S + (col - 1536)] = v;
          h1b[(size_t)(row + r) * H1S + (col - 1536)] = __float2bfloat16(v);
        }
      }
    }
  }
  if (blockIdx.x < HEADBLKS) {
#pragma unroll
    for (int off = 1; off < 16; off <<= 1)
#pragma unroll
      for (int m = 0; m < 4; ++m)
#pragma unroll
        for (int r = 0; r < 4; ++r) srun[m][r] += __shfl_xor(srun[m][r], off);
    __syncthreads();
    if (wc == 0 && (lane & 15) == 0) {
#pragma unroll
      for (int m = 0; m < 4; ++m)
#pragma unroll
        for (int r = 0; r < 4; ++r)
          reds[wr * 64 + m * 16 + (lane >> 4) * 4 + r] = srun[m][r];
    }
    __syncthreads();
    if (wc == 1 && (lane & 15) == 0) {
#pragma unroll
      for (int m = 0; m < 4; ++m)
#pragma unroll
        for (int r = 0; r < 4; ++r) {
          int row = wr * 64 + m * 16 + (lane >> 4) * 4 + r;
          ps_head[(size_t)blockIdx.x * NTOK + row0 + row] = reds[row] + srun[m][r];
        }
    }
  }
}

// ---------- tail0 (H=512): R2-verified structure ----------
template <int H, int OSZ, int JSPLIT>
__global__ __launch_bounds__(256, 2) void tail_lse_mfma(
    const bf16* __restrict__ Ab, const bf16* __restrict__ W2b,
    float* __restrict__ ps) {
  __shared__ __align__(16) char As[128 * 128];
  __shared__ __align__(16) char Bs[128 * 128];
  __shared__ float reds[128];
  int tid = threadIdx.x;
  int lane = tid & 63, wave = tid >> 6;
  int wr = wave >> 1, wc = wave & 1;
  int tok0 = blockIdx.x * 128;
  const int NT = (OSZ + 127) / 128;
  const int TPS = (NT + JSPLIT - 1) / JSPLIT;
  int t_lo = blockIdx.y * TPS;
  int t_hi = min(NT, t_lo + TPS);
  float srun[4][4] = {};
  for (int jt = t_lo; jt < t_hi; ++jt) {
    int j0 = jt * 128;
    f32x4 acc[4][4] = {};
    for (int k0 = 0; k0 < H; k0 += 64) {
      __syncthreads();
      stage_tile(Ab, tok0, NTOK - 1, H, k0, As, wave, lane);
      stage_tile(W2b, j0, OSZ - 1, H, k0, Bs, wave, lane);
      __syncthreads();
#pragma unroll
      for (int kk = 0; kk < 2; ++kk) {
        short8v af[4], bfr[4];
#pragma unroll
        for (int m = 0; m < 4; ++m)
          af[m] = read_frag(As, wr * 64 + m * 16 + (lane & 15), kk, lane);
#pragma unroll
        for (int n = 0; n < 4; ++n)
          bfr[n] = read_frag(Bs, wc * 64 + n * 16 + (lane & 15), kk, lane);
#pragma unroll
        for (int m = 0; m < 4; ++m)
#pragma unroll
          for (int n = 0; n < 4; ++n)
            acc[m][n] = __builtin_amdgcn_mfma_f32_16x16x32_bf16(af[m], bfr[n], acc[m][n], 0, 0, 0);
      }
    }
#pragma unroll
    for (int m = 0; m < 4; ++m)
#pragma unroll
      for (int n = 0; n < 4; ++n) {
        int col = j0 + wc * 64 + n * 16 + (lane & 15);
        if (col < OSZ) {
#pragma unroll
          for (int r = 0; r < 4; ++r) srun[m][r] += __expf(acc[m][n][r]);
        }
      }
  }
#pragma unroll
  for (int off = 1; off < 16; off <<= 1)
#pragma unroll
    for (int m = 0; m < 4; ++m)
#pragma unroll
      for (int r = 0; r < 4; ++r) srun[m][r] += __shfl_xor(srun[m][r], off);
  __syncthreads();
  if (wc == 0 && (lane & 15) == 0) {
#pragma unroll
    for (int m = 0; m < 4; ++m)
#pragma unroll
      for (int r = 0; r < 4; ++r)
        reds[wr * 64 + m * 16 + (lane >> 4) * 4 + r] = srun[m][r];
  }
  __syncthreads();
  if (wc == 1 && (lane & 15) == 0) {
#pragma unroll
    for (int m = 0; m < 4; ++m)
#pragma unroll
      for (int r = 0; r < 4; ++r) {
        int row = wr * 64 + m * 16 + (lane >> 4) * 4 + r;
        ps[(size_t)blockIdx.y * NTOK + tok0 + row] = reds[row] + srun[m][r];
      }
  }
}

// ---------- tail1 (H=128): A-in-registers, double-buffered B stream,
// counted vmcnt + raw barriers (prefetch never drained) ----------
__global__ __launch_bounds__(256, 2) void tail1_lse(
    const bf16* __restrict__ Ab, const bf16* __restrict__ W2b,
    float* __restrict__ ps) {
  __shared__ __align__(16) char ldsA[32 * 1024];
  __shared__ __align__(16) char ldsB[32 * 1024];
  __shared__ float reds[128];
  int tid = threadIdx.x;
  int lane = tid & 63, wave = tid >> 6;
  int wr = wave >> 1, wc = wave & 1;
  int tok0 = blockIdx.x * 128;
  const int NT = (OSZ1 + 127) / 128;       // 315
  const int TPS = (NT + JS1 - 1) / JS1;    // 20
  int t_lo = blockIdx.y * TPS;
  int t_hi = min(NT, t_lo + TPS);
  int nt = t_hi - t_lo;

  // Stage A (128 tokens x K=128) once; consume into registers.
  stage_tile256(Ab, tok0, NTOK - 1, H1S, ldsA, wave, lane);
  WAIT_VM(0); SCHED_FENCE();
  RAW_BAR();
  short8v afr[4][4];  // [kk][m]
#pragma unroll
  for (int kk = 0; kk < 4; ++kk)
#pragma unroll
    for (int m = 0; m < 4; ++m)
      afr[kk][m] = read_frag256(ldsA, wr * 64 + m * 16 + (lane & 15), kk, lane);
  stage_tile256(W2b, t_lo * 128, OSZ1 - 1, H1S, ldsB, wave, lane);
  WAIT_LGKM0(); SCHED_FENCE();   // A-frag reads complete before ldsA is reused
  RAW_BAR();
  if (nt > 1) stage_tile256(W2b, (t_lo + 1) * 128, OSZ1 - 1, H1S, ldsA, wave, lane);

  float srun[4][4] = {};
  for (int i = 0; i < nt; ++i) {
    char* cur = (i & 1) ? ldsA : ldsB;
    if (i + 1 < nt) { WAIT_VM(8); } else { WAIT_VM(0); }
    SCHED_FENCE();
    RAW_BAR();
    int j0 = (t_lo + i) * 128;
    f32x4 acc[4][4] = {};
#pragma unroll
    for (int kk = 0; kk < 4; ++kk) {
      short8v bfr[4];
#pragma unroll
      for (int n = 0; n < 4; ++n)
        bfr[n] = read_frag256(cur, wc * 64 + n * 16 + (lane & 15), kk, lane);
#pragma unroll
      for (int m = 0; m < 4; ++m)
#pragma unroll
        for (int n = 0; n < 4; ++n)
          acc[m][n] = __builtin_amdgcn_mfma_f32_16x16x32_bf16(afr[kk][m], bfr[n], acc[m][n], 0, 0, 0);
    }
#pragma unroll
    for (int m = 0; m < 4; ++m)
#pragma unroll
      for (int n = 0; n < 4; ++n) {
        int col = j0 + wc * 64 + n * 16 + (lane & 15);
        if (col < OSZ1) {
#pragma unroll
          for (int r = 0; r < 4; ++r) srun[m][r] += __expf(acc[m][n][r]);
        }
      }
    SCHED_FENCE();
    RAW_BAR();  // all waves done reading cur
    if (i + 2 < nt) stage_tile256(W2b, (t_lo + i + 2) * 128, OSZ1 - 1, H1S, cur, wave, lane);
  }
#pragma unroll
  for (int off = 1; off < 16; off <<= 1)
#pragma unroll
    for (int m = 0; m < 4; ++m)
#pragma unroll
      for (int r = 0; r < 4; ++r) srun[m][r] += __shfl_xor(srun[m][r], off);
  __syncthreads();
  if (wc == 0 && (lane & 15) == 0) {
#pragma unroll
    for (int m = 0; m < 4; ++m)
#pragma unroll
      for (int r = 0; r < 4; ++r)
        reds[wr * 64 + m * 16 + (lane >> 4) * 4 + r] = srun[m][r];
  }
  __syncthreads();
  if (wc == 1 && (lane & 15) == 0) {
#pragma unroll
    for (int m = 0; m < 4; ++m)
#pragma unroll
      for (int r = 0; r < 4; ++r) {
        int row = wr * 64 + m * 16 + (lane >> 4) * 4 + r;
        ps[(size_t)blockIdx.y * NTOK + tok0 + row] = reds[row] + srun[m][r];
      }
  }
}

// ---------- finalize: one wave per token ----------
__global__ __launch_bounds__(256) void finalize2(
    const int* __restrict__ target, const float* __restrict__ head,
    const float* __restrict__ ps_head,
    const float* __restrict__ h0, const float* __restrict__ h1,
    const float* __restrict__ W2_0, const float* __restrict__ W2_1,
    const float* __restrict__ ps0, const float* __restrict__ ps1,
    float* __restrict__ out) {
  int warp = threadIdx.x >> 6, lane = threadIdx.x & 63;
  int i = blockIdx.x * 4 + warp;
  if (i >= NTOK) return;
  int t = target[i];
  float sh = 0.f;
#pragma unroll
  for (int s = 0; s < HEADBLKS; ++s) sh += ps_head[(size_t)s * NTOK + i];
  float lse_head = logf(sh);
  float res;
  if (t < C0LO) {
    res = head[(size_t)i * NHEAD + t] - lse_head;
  } else {
    int c = (t < C0HI) ? 0 : 1;
    int H = c ? H1S : H0S;
    int low = c ? C0HI : C0LO;
    const float* hv = (c ? h1 : h0) + (size_t)i * H;
    const float* wv = (c ? W2_1 : W2_0) + (size_t)(t - low) * H;
    float p = 0.f;
    for (int k = lane * 4; k < H; k += 256) {
      float4 a = *reinterpret_cast<const float4*>(hv + k);
      float4 b = *reinterpret_cast<const float4*>(wv + k);
      p += a.x * b.x + a.y * b.y + a.z * b.z + a.w * b.w;
    }
#pragma unroll
    for (int off = 32; off > 0; off >>= 1) p += __shfl_xor(p, off);
    const float* ps = c ? ps1 : ps0;
    float S = 0.f;
    for (int s = 0; s < JS0; ++s) S += ps[(size_t)s * NTOK + i];
    float cl = head[(size_t)i * NHEAD + C0LO + c];
    res = (cl - lse_head) + (p - logf(S));
  }
  if (lane == 0) out[i] = res;
}

__global__ __launch_bounds__(256) void loss_kernel(float* __restrict__ out) {
  __shared__ float red[256];
  int tid = threadIdx.x;
  float s = 0.f;
  for (int j = tid; j < NTOK; j += 256) s += out[j];
  red[tid] = s; __syncthreads();
  for (int off = 128; off > 0; off >>= 1) {
    if (tid < off) red[tid] += red[tid + off];
    __syncthreads();
  }
  if (tid == 0) out[NTOK] = -red[0] / (float)NTOK;
}

extern "C" void kernel_launch(void* const* d_in, const int* in_sizes, int n_in,
                              void* d_out, int out_size, void* d_ws, size_t ws_size,
                              hipStream_t stream) {
  (void)in_sizes; (void)n_in; (void)out_size; (void)ws_size;
  const float* x = (const float*)d_in[0];
  const int* target = (const int*)d_in[1];
  const float* W_head = (const float*)d_in[2];
  const float* W1_0 = (const float*)d_in[3];
  const float* W2_0 = (const float*)d_in[4];
  const float* W1_1 = (const float*)d_in[5];
  const float* W2_1 = (const float*)d_in[6];
  float* out = (float*)d_out;

  char* w = (char*)d_ws;
  size_t off = 0;
  auto alloc = [&](size_t bytes) -> void* {
    void* p = w + off;
    off = (off + bytes + 255) & ~(size_t)255;
    return p;
  };
  bf16* xb   = (bf16*)alloc((size_t)NTOK * DIM * 2);
  bf16* Wcat = (bf16*)alloc((size_t)NCAT * DIM * 2);
  bf16* W20b = (bf16*)alloc((size_t)OSZ0 * H0S * 2);
  bf16* W21b = (bf16*)alloc((size_t)OSZ1 * H1S * 2);
  float* head = (float*)alloc((size_t)NTOK * NHEAD * 4);
  float* h0   = (float*)alloc((size_t)NTOK * H0S * 4);
  bf16*  h0b  = (bf16*)alloc((size_t)NTOK * H0S * 2);
  float* h1   = (float*)alloc((size_t)NTOK * H1S * 4);
  bf16*  h1b  = (bf16*)alloc((size_t)NTOK * H1S * 2);
  float* ps_head = (float*)alloc((size_t)HEADBLKS * NTOK * 4);
  float* ps0 = (float*)alloc((size_t)JS0 * NTOK * 4);
  float* ps1 = (float*)alloc((size_t)JS1 * NTOK * 4);

  dim3 blk(256);
  const long TOT8 = (long)NTOK * DIM / 8 + (long)NCAT * DIM / 8 +
                    (long)OSZ0 * H0S / 8 + (long)OSZ1 * H1S / 8;
  cvt_all<<<dim3((unsigned)((TOT8 + 255) / 256)), blk, 0, stream>>>(
      x, W_head, W1_0, W1_1, W2_0, W2_1, xb, Wcat, W20b, W21b);

  proj_gemm<<<dim3(NCAT / 128, NTOK / 128), blk, 0, stream>>>(
      xb, Wcat, head, h0, h0b, h1, h1b, ps_head);

  tail_lse_mfma<H0S, OSZ0, JS0><<<dim3(NTOK / 128, JS0), blk, 0, stream>>>(h0b, W20b, ps0);
  tail1_lse<<<dim3(NTOK / 128, JS1), blk, 0, stream>>>(h1b, W21b, ps1);

  finalize2<<<dim3(NTOK / 4), blk, 0, stream>>>(target, head, ps_head, h0, h1,
                                                W2_0, W2_1, ps0, ps1, out);
  loss_kernel<<<1, blk, 0, stream>>>(out);
}